// Round 16
// baseline (416.684 us; speedup 1.0000x reference)
//
#include <hip/hip_runtime.h>
#include <hip/hip_bf16.h>

#define DEV __device__ __forceinline__

typedef __bf16 bf16_t;
typedef __bf16 bf16x8 __attribute__((ext_vector_type(8)));
typedef __bf16 bf16x4 __attribute__((ext_vector_type(4)));
typedef __bf16 bf16x2 __attribute__((ext_vector_type(2)));
typedef float f32x4 __attribute__((ext_vector_type(4)));
typedef float f32x16 __attribute__((ext_vector_type(16)));
typedef unsigned int u32;
typedef unsigned short u16;
typedef u32 u32x4 __attribute__((ext_vector_type(4)));

constexpr int D_MODEL = 2048;
constexpr int SEQ = 2048;
constexpr int BATCH = 4;
constexpr int N_HEADS = 16;
constexpr int HEAD_DIM = 128;
constexpr int TOK = BATCH * SEQ; // 8192

DEV void gload_lds16(const void* g, void* l) {
  __builtin_amdgcn_global_load_lds(
      (const __attribute__((address_space(1))) unsigned int*)g,
      (__attribute__((address_space(3))) unsigned int*)l, 16, 0, 0);
}

DEV float fast_exp2(float x) {
#if __has_builtin(__builtin_amdgcn_exp2f)
  return __builtin_amdgcn_exp2f(x);
#else
  return exp2f(x);
#endif
}

DEV u32 pack2(float lo, float hi) {
  u16 a = __builtin_bit_cast(u16, (bf16_t)lo);
  u16 b = __builtin_bit_cast(u16, (bf16_t)hi);
  return (u32)a | ((u32)b << 16);
}

#define MFMA16(a, b, c) __builtin_amdgcn_mfma_f32_16x16x32_bf16((a), (b), (c), 0, 0, 0)
#define MFMA32(a, b, c) __builtin_amdgcn_mfma_f32_32x32x16_bf16((a), (b), (c), 0, 0, 0)

// ------- merged pre-pass: z=0..3 transpose W -> bf16 [N][K]; z=4 cvt x -> bf16 -------
// 64x64 tiles, bf16x2 stores (full 128B write lines). Verified R12.
__global__ void k_prep(const float* __restrict__ x, bf16_t* __restrict__ xb,
                       const float* __restrict__ Wq, const float* __restrict__ Wk,
                       const float* __restrict__ Wv, const float* __restrict__ Wo,
                       bf16_t* __restrict__ WqkvT, bf16_t* __restrict__ WoT) {
  const int z = blockIdx.z;
  if (z < 4) {
    __shared__ float t[64][65];
    const float* W = z == 0 ? Wq : z == 1 ? Wk : z == 2 ? Wv : Wo;
    bf16_t* Wt = z < 3 ? WqkvT + (size_t)z * D_MODEL * D_MODEL : WoT;
    int k0 = blockIdx.x * 64, n0 = blockIdx.y * 64;
    int tx = threadIdx.x, ty = threadIdx.y;
#pragma unroll
    for (int e = 0; e < 16; ++e) {
      int r = ty + (e >> 1) * 8;
      int c = tx + (e & 1) * 32;
      t[r][c] = W[(size_t)(k0 + r) * D_MODEL + n0 + c];
    }
    __syncthreads();
#pragma unroll
    for (int e = 0; e < 8; ++e) {
      int rr = ty + e * 8;
      int cc = tx * 2;
      bf16x2 ov;
      ov[0] = (bf16_t)t[cc][rr];
      ov[1] = (bf16_t)t[cc + 1][rr];
      *(bf16x2*)(Wt + (size_t)(n0 + rr) * D_MODEL + k0 + cc) = ov;
    }
  } else {
    const int n4 = TOK * D_MODEL / 4;
    const int tid = threadIdx.y * 32 + threadIdx.x;
    int i = (blockIdx.y * 32 + blockIdx.x) * 256 + tid;
    const int stride = 32 * 32 * 256;
    for (; i < n4; i += stride) {
      float4 v = ((const float4*)x)[i];
      bf16x4 o;
      o[0] = (bf16_t)v.x; o[1] = (bf16_t)v.y; o[2] = (bf16_t)v.z; o[3] = (bf16_t)v.w;
      ((bf16x4*)xb)[i] = o;
    }
  }
}

// ---------------- 256x256 8-wave GEMM, 2-phase K-step (R6/R9-proven: 201us) ----------
// The ~46% MfmaUtil / 201us attractor survived EIGHT structural interventions.
// This is the verified floor for this tile geometry. DO NOT restructure.
// launch_bounds stays (512,2): (512,4) caps VGPR at 128 -> acc spills (R3).
// MODE 0 writes Q pre-scaled by C = log2(e)/sqrt(128) (softmax scale folded).
template <int MODE>
__global__ __launch_bounds__(512, 2) void k_gemm256(const bf16_t* __restrict__ A,
                                                    const bf16_t* __restrict__ Bt,
                                                    const float* __restrict__ b0p,
                                                    const float* __restrict__ b1p,
                                                    const float* __restrict__ b2p,
                                                    void* __restrict__ o0,
                                                    void* __restrict__ o1,
                                                    void* __restrict__ o2) {
  constexpr int K = D_MODEL;
  constexpr int NTOT = (MODE == 0) ? 3 * D_MODEL : D_MODEL;
  constexpr int NT = K / 64; // 32 K-tiles
  constexpr int NBM = TOK / 256; // 32
  __shared__ __attribute__((aligned(16))) bf16_t sh[2][2][2][8192];

  const int bid = blockIdx.x;
  const int cpx = gridDim.x >> 3;
  const int swz = (bid & 7) * cpx + (bid >> 3);
  const int grp = swz / (NBM * 4);
  const int rem = swz % (NBM * 4);
  const int bm = rem >> 2;
  const int bn = grp * 4 + (rem & 3);

  const int tid = threadIdx.x;
  const int lane = tid & 63;
  const int w = tid >> 6;
  const int wm = w >> 2, wn = w & 3;
  const int lr = lane & 15, lg = lane >> 4;

  const bf16_t* Agl[2];
  const bf16_t* Bgl[2];
  int ldsg[2];
#pragma unroll
  for (int l = 0; l < 2; ++l) {
    int g = l * 512 + tid;
    int r = g >> 2, c = g & 3;
    int csw = c ^ ((r ^ (r >> 2)) & 3);
    Agl[l] = A + (size_t)(bm * 256 + r) * K + csw * 8;
    Bgl[l] = Bt + (size_t)(bn * 256 + r) * K + csw * 8;
    ldsg[l] = g * 8;
  }

  auto SA = [&](int buf, int t, int kh) {
    const int off = t * 64 + kh * 32;
#pragma unroll
    for (int l = 0; l < 2; ++l) gload_lds16(Agl[l] + off, &sh[buf][0][kh][ldsg[l]]);
  };
  auto SB = [&](int buf, int t, int kh) {
    const int off = t * 64 + kh * 32;
#pragma unroll
    for (int l = 0; l < 2; ++l) gload_lds16(Bgl[l] + off, &sh[buf][1][kh][ldsg[l]]);
  };

  int offA[8], offB[4];
  const int cx = lg ^ ((lr ^ (lr >> 2)) & 3);
#pragma unroll
  for (int i = 0; i < 8; ++i) offA[i] = (wm * 128 + i * 16 + lr) * 32 + cx * 8;
#pragma unroll
  for (int j = 0; j < 4; ++j) offB[j] = (wn * 64 + j * 16 + lr) * 32 + cx * 8;

  f32x4 acc[8][4] = {};
  bf16x8 af[8], bf_[4];

  SA(0, 0, 0); SB(0, 0, 0); SA(0, 0, 1); SB(0, 0, 1);

#define MFMA_ROW(i)                                  \
  acc[i][0] = MFMA16(af[i], bf_[0], acc[i][0]);      \
  acc[i][1] = MFMA16(af[i], bf_[1], acc[i][1]);      \
  acc[i][2] = MFMA16(af[i], bf_[2], acc[i][2]);      \
  acc[i][3] = MFMA16(af[i], bf_[3], acc[i][3]);

  for (int t = 0; t < NT; ++t) {
    const int cur = t & 1, nxt = cur ^ 1;
    const int t1 = (t + 1 < NT) ? t + 1 : NT - 1;
#pragma unroll
    for (int kh = 0; kh < 2; ++kh) {
      asm volatile("s_waitcnt vmcnt(4)" ::: "memory");
      __builtin_amdgcn_s_barrier();
#pragma unroll
      for (int j = 0; j < 4; ++j) bf_[j] = *(const bf16x8*)&sh[cur][1][kh][offB[j]];
#pragma unroll
      for (int i = 0; i < 8; ++i) af[i] = *(const bf16x8*)&sh[cur][0][kh][offA[i]];
      SA(nxt, t1, kh);
      SB(nxt, t1, kh);
      __builtin_amdgcn_s_setprio(1);
      asm volatile("s_waitcnt lgkmcnt(6)" ::: "memory");
      __builtin_amdgcn_sched_barrier(0);
      MFMA_ROW(0) MFMA_ROW(1)
      asm volatile("s_waitcnt lgkmcnt(4)" ::: "memory");
      __builtin_amdgcn_sched_barrier(0);
      MFMA_ROW(2) MFMA_ROW(3)
      asm volatile("s_waitcnt lgkmcnt(2)" ::: "memory");
      __builtin_amdgcn_sched_barrier(0);
      MFMA_ROW(4) MFMA_ROW(5)
      asm volatile("s_waitcnt lgkmcnt(0)" ::: "memory");
      __builtin_amdgcn_sched_barrier(0);
      MFMA_ROW(6) MFMA_ROW(7)
      __builtin_amdgcn_s_setprio(0);
    }
  }
#undef MFMA_ROW

  asm volatile("s_waitcnt vmcnt(0) lgkmcnt(0)" ::: "memory");

  // ---- epilogue ----
  const float CQ = 0.12751949848078418f; // (1/sqrt(128)) * log2(e), folded into Q
#pragma unroll
  for (int i = 0; i < 8; ++i) {
    const int row = bm * 256 + wm * 128 + i * 16 + lg * 4;
#pragma unroll
    for (int jn = 0; jn < 4; ++jn) {
      const int col = bn * 256 + wn * 64 + jn * 16 + lr;
      if (MODE == 1) {
        const float bv = b0p[col];
        float* Cf = (float*)o0;
#pragma unroll
        for (int j = 0; j < 4; ++j)
          Cf[(size_t)(row + j) * D_MODEL + col] = acc[i][jn][j] + bv;
      } else {
        const int sel = col >> 11, cl = col & 2047;
        const float bv = (sel == 0 ? b0p : sel == 1 ? b1p : b2p)[cl];
        if (sel < 2) {
          const float scl = (sel == 0) ? CQ : 1.0f;
          bf16_t* dst = (bf16_t*)(sel == 0 ? o0 : o1);
#pragma unroll
          for (int j = 0; j < 4; ++j)
            dst[(size_t)(row + j) * D_MODEL + cl] = (bf16_t)((acc[i][jn][j] + bv) * scl);
        } else {
          const int bb2 = row >> 11, s = row & 2047;
          bf16x4 ov;
#pragma unroll
          for (int j = 0; j < 4; ++j) ov[j] = (bf16_t)(acc[i][jn][j] + bv);
          bf16_t* Vt = (bf16_t*)o2;
          *(bf16x4*)(Vt + (((size_t)(bb2 * 16 + (cl >> 7))) * 128 + (cl & 127)) * 2048 + s) = ov;
        }
      }
    }
  }
}

// -------- causal flash attention: 8 waves/block (QROWS=256), KVBLK=32, 3-slot ring --------
// R16: same per-wave code as the verified champion (QBLK=32, swapped QK^T,
// defer-max, shfl_xor exchange); K/V re-read halving achieved via 8 WAVES
// sharing the staged tile through LDS (NOT the falsified 2-q-group register
// sharing). 512 blocks: qb = 7-(fid>>6) (heaviest first), bh = fid&63.
// Wave w owns rows qw0 = qb*256 + w*32; nt = 8qb+8. Staging traffic 557->278MB.
// STAGE: 512 threads cover 512 K-chunks + 512 V-chunks in one pass ->
// 2 VMEM/thread/stage (was 4) -> steady-state wait is vmcnt(2) (re-derived).
// launch_bounds (512,1): NO tighter bound — (512,2) would cap VGPR at 128 and
// spill (~168 needed, R3 lesson). Occupancy 1 block/CU (8 waves).
__global__ __launch_bounds__(512, 1) void k_attn(const bf16_t* __restrict__ Q,
                                                 const bf16_t* __restrict__ K,
                                                 const bf16_t* __restrict__ Vt,
                                                 bf16_t* __restrict__ AO) {
  const int fid = blockIdx.x;          // 512 blocks
  const int qb = 7 - (fid >> 6);       // heaviest first
  const int bh = fid & 63;
  const int b = bh >> 4, h = bh & 15;
  const int w = threadIdx.x >> 6, lane = threadIdx.x & 63;  // w = 0..7
  const int l31 = lane & 31, hl = lane >> 5;
  const int nt = 8 * qb + 8;           // >= 8 always

  __shared__ __attribute__((aligned(16))) bf16_t Ks[3][32 * 128];
  __shared__ __attribute__((aligned(16))) bf16_t Vs[3][128 * 32];

  const bf16_t* kbase = K + (size_t)(b * SEQ) * D_MODEL + h * HEAD_DIM;
  const bf16_t* vtbase = Vt + (size_t)bh * HEAD_DIM * SEQ;

  auto STAGE = [&](int buf, int kt) {
    const int tt = threadIdx.x;        // 0..511
    {
      int r = tt >> 4, c = tt & 15;    // K tile: 32 rows x 16 chunks
      gload_lds16(kbase + (size_t)(kt * 32 + r) * D_MODEL + ((c ^ (r & 7)) * 8),
                  &Ks[buf][(size_t)(tt & ~63) * 8]);
    }
    {
      int r = tt >> 2, c = tt & 3;     // V^T tile: 128 rows x 4 chunks
      gload_lds16(vtbase + (size_t)r * SEQ + kt * 32 + ((c ^ ((r ^ (r >> 2)) & 3)) * 8),
                  &Vs[buf][(size_t)(tt & ~63) * 8]);
    }
  };

  const int qw0 = qb * 256 + w * 32;
  const int qa = qw0 + l31;

  const bf16_t* qp = Q + (size_t)(b * SEQ + qa) * D_MODEL + h * HEAD_DIM + hl * 8;
  bf16x8 qf[8];
#pragma unroll
  for (int step = 0; step < 8; ++step) qf[step] = *(const bf16x8*)(qp + step * 16);

  f32x16 oacc[4];
#pragma unroll
  for (int db = 0; db < 4; ++db)
#pragma unroll
    for (int r = 0; r < 16; ++r) oacc[db][r] = 0.f;
  float m = -1e30f, lsum = 0.f; // lsum: lane-local partial (combined in epilogue)

  STAGE(0, 0);
  STAGE(1, 1); // nt >= 8, always valid

  int cur = 0, stg = 2; // stage slot = (kt+2) % 3
  for (int kt = 0; kt < nt; ++kt) {
    if (kt < nt - 1) {
      asm volatile("s_waitcnt vmcnt(2)" ::: "memory"); // drain stage(kt) [2/stage]
    } else {
      asm volatile("s_waitcnt vmcnt(0)" ::: "memory"); // final tile
    }
    __builtin_amdgcn_s_barrier();
    asm volatile("" ::: "memory");
    if (kt + 2 < nt) STAGE(stg, kt + 2);

    if (kt * 32 < qw0 + 32) {
      // ---- swapped QK^T (Q pre-scaled by C in GEMM epilogue) ----
      f32x16 sacc;
#pragma unroll
      for (int r = 0; r < 16; ++r) sacc[r] = 0.f;
      const bf16_t* kr = &Ks[cur][l31 * 128];
      const int rx = l31 & 7;
      __builtin_amdgcn_s_setprio(1);
#pragma unroll
      for (int step = 0; step < 8; ++step) {
        bf16x8 kf = *(const bf16x8*)(kr + (((step * 2 + hl) ^ rx) * 8));
        sacc = MFMA32(kf, qf[step], sacc);
      }
      __builtin_amdgcn_s_setprio(0);

      // ---- mask + tile max (max3-fused tree) ----
      const bool domask = (kt * 32 + 31 > qw0);
      if (domask) {
#pragma unroll
        for (int r = 0; r < 16; ++r) {
          int kv = kt * 32 + 4 * hl + (r & 3) + 8 * (r >> 2);
          if (kv > qa) sacc[r] = -1e30f;
        }
      }
      float mx8[8];
#pragma unroll
      for (int r = 0; r < 8; ++r) mx8[r] = fmaxf(sacc[r], sacc[r + 8]);
      float t0 = fmaxf(fmaxf(mx8[0], mx8[1]), mx8[2]);
      float t1 = fmaxf(fmaxf(mx8[3], mx8[4]), mx8[5]);
      float t2 = fmaxf(fmaxf(mx8[6], mx8[7]), t0);
      float tm = fmaxf(t1, t2);
      tm = fmaxf(tm, __shfl_xor(tm, 32));

      // ---- defer-max rescale (threshold 12.5: P <= 2^12.5, f32/bf16-safe) ----
      if (!__all(tm <= m + 12.5f)) {
        const float mn = fmaxf(m, tm);
        const float al = fast_exp2(m - mn);
        lsum *= al;
#pragma unroll
        for (int db = 0; db < 4; ++db)
#pragma unroll
          for (int r = 0; r < 16; ++r) oacc[db][r] *= al;
        m = mn;
      }

      // ---- P = exp2(S - m), lane-local sum (tree) ----
#pragma unroll
      for (int r = 0; r < 16; ++r) sacc[r] = fast_exp2(sacc[r] - m);
      float sm8[8];
#pragma unroll
      for (int r = 0; r < 8; ++r) sm8[r] = sacc[r] + sacc[r + 8];
#pragma unroll
      for (int r = 0; r < 4; ++r) sm8[r] = sm8[r] + sm8[r + 4];
      lsum += (sm8[0] + sm8[1]) + (sm8[2] + sm8[3]);

      // ---- P^T -> bf16 B-operand (shfl_xor exchange) ----
      bf16x8 pb[2];
#pragma unroll
      for (int ck = 0; ck < 2; ++ck) {
        u32 a0 = pack2(sacc[8 * ck + 0], sacc[8 * ck + 1]);
        u32 a1 = pack2(sacc[8 * ck + 2], sacc[8 * ck + 3]);
        u32 b0 = pack2(sacc[8 * ck + 4], sacc[8 * ck + 5]);
        u32 b1 = pack2(sacc[8 * ck + 6], sacc[8 * ck + 7]);
        u32 send0 = hl ? a0 : b0, send1 = hl ? a1 : b1;
        u32 keep0 = hl ? b0 : a0, keep1 = hl ? b1 : a1;
        u32 r0 = __shfl_xor(send0, 32), r1 = __shfl_xor(send1, 32);
        u32x4 fv;
        fv[0] = hl ? r0 : keep0;
        fv[1] = hl ? r1 : keep1;
        fv[2] = hl ? keep0 : r0;
        fv[3] = hl ? keep1 : r1;
        pb[ck] = __builtin_bit_cast(bf16x8, fv);
      }

      // ---- PV ----
      __builtin_amdgcn_s_setprio(1);
#pragma unroll
      for (int db = 0; db < 4; ++db) {
        const int vrow = db * 32 + l31;
        const bf16_t* vr = &Vs[cur][vrow * 32];
        const int vx = (vrow ^ (vrow >> 2)) & 3;
#pragma unroll
        for (int ck = 0; ck < 2; ++ck) {
          bf16x8 vf = *(const bf16x8*)(vr + (((ck * 2 + hl) ^ vx) * 8));
          oacc[db] = MFMA32(vf, pb[ck], oacc[db]);
        }
      }
      __builtin_amdgcn_s_setprio(0);
    }

    cur = (cur == 2) ? 0 : cur + 1;
    stg = (stg == 2) ? 0 : stg + 1;
  }

  // ---- epilogue (combine lane-pair lsum partials once) ----
  const float inv = 1.f / (lsum + __shfl_xor(lsum, 32));
  bf16_t* ao = AO + (size_t)(b * SEQ + qa) * D_MODEL + h * HEAD_DIM;
#pragma unroll
  for (int db = 0; db < 4; ++db)
#pragma unroll
    for (int g = 0; g < 4; ++g) {
      bf16x4 ov;
#pragma unroll
      for (int j = 0; j < 4; ++j) ov[j] = (bf16_t)(oacc[db][4 * g + j] * inv);
      *(bf16x4*)(ao + db * 32 + 8 * g + 4 * hl) = ov;
    }
}

// ---------------- launch ----------------
extern "C" void kernel_launch(void* const* d_in, const int* in_sizes, int n_in,
                              void* d_out, int out_size, void* d_ws, size_t ws_size,
                              hipStream_t stream) {
  const float* x  = (const float*)d_in[0];
  const float* Wq = (const float*)d_in[1];
  const float* bq = (const float*)d_in[2];
  const float* Wk = (const float*)d_in[3];
  const float* bk = (const float*)d_in[4];
  const float* Wv = (const float*)d_in[5];
  const float* bv = (const float*)d_in[6];
  const float* Wo = (const float*)d_in[7];
  const float* bo = (const float*)d_in[8];

  const size_t SZ_X = (size_t)TOK * D_MODEL * sizeof(bf16_t);       // 32 MB
  const size_t SZ_W = (size_t)D_MODEL * D_MODEL * sizeof(bf16_t);   // 8 MB

  char* p = (char*)d_ws;
  bf16_t* xb    = (bf16_t*)p;                     p += SZ_X;
  bf16_t* WqkvT = (bf16_t*)p;                     p += 3 * SZ_W;
  bf16_t* WoT   = (bf16_t*)p;                     p += SZ_W;
  bf16_t* Qm    = (bf16_t*)p;                     p += SZ_X;
  bf16_t* Km    = (bf16_t*)p;                     p += SZ_X;
  bf16_t* Vt    = (bf16_t*)p;                     p += SZ_X;
  bf16_t* AO    = xb;  // xb dead after QKV GEMM

  // merged cvt + weight transpose (z=0..3 transpose 64x64, z=4 cvt)
  k_prep<<<dim3(32, 32, 5), dim3(32, 8), 0, stream>>>(x, xb, Wq, Wk, Wv, Wo, WqkvT, WoT);

  const int gqkv = (TOK / 256) * (3 * D_MODEL / 256); // 32*24 = 768
  k_gemm256<0><<<gqkv, 512, 0, stream>>>(xb, WqkvT, bq, bk, bv, Qm, Km, Vt);

  k_attn<<<512, 512, 0, stream>>>(Qm, Km, Vt, AO);

  const int go = (TOK / 256) * (D_MODEL / 256); // 256
  k_gemm256<1><<<go, 512, 0, stream>>>(AO, WoT, bo, nullptr, nullptr, d_out, nullptr, nullptr);
}

// Round 17
// 394.399 us; speedup vs baseline: 1.0565x; 1.0565x over previous
//
#include <hip/hip_runtime.h>
#include <hip/hip_bf16.h>

#define DEV __device__ __forceinline__

typedef __bf16 bf16_t;
typedef __bf16 bf16x8 __attribute__((ext_vector_type(8)));
typedef __bf16 bf16x4 __attribute__((ext_vector_type(4)));
typedef __bf16 bf16x2 __attribute__((ext_vector_type(2)));
typedef float f32x4 __attribute__((ext_vector_type(4)));
typedef float f32x16 __attribute__((ext_vector_type(16)));
typedef unsigned int u32;
typedef unsigned short u16;
typedef u32 u32x4 __attribute__((ext_vector_type(4)));

constexpr int D_MODEL = 2048;
constexpr int SEQ = 2048;
constexpr int BATCH = 4;
constexpr int N_HEADS = 16;
constexpr int HEAD_DIM = 128;
constexpr int TOK = BATCH * SEQ; // 8192

DEV void gload_lds16(const void* g, void* l) {
  __builtin_amdgcn_global_load_lds(
      (const __attribute__((address_space(1))) unsigned int*)g,
      (__attribute__((address_space(3))) unsigned int*)l, 16, 0, 0);
}

DEV float fast_exp2(float x) {
#if __has_builtin(__builtin_amdgcn_exp2f)
  return __builtin_amdgcn_exp2f(x);
#else
  return exp2f(x);
#endif
}

DEV u32 pack2(float lo, float hi) {
  u16 a = __builtin_bit_cast(u16, (bf16_t)lo);
  u16 b = __builtin_bit_cast(u16, (bf16_t)hi);
  return (u32)a | ((u32)b << 16);
}

#define MFMA16(a, b, c) __builtin_amdgcn_mfma_f32_16x16x32_bf16((a), (b), (c), 0, 0, 0)
#define MFMA32(a, b, c) __builtin_amdgcn_mfma_f32_32x32x16_bf16((a), (b), (c), 0, 0, 0)

// ------- merged pre-pass: z=0..3 transpose W -> bf16 [N][K]; z=4 cvt x -> bf16 -------
// 64x64 tiles, bf16x2 stores (full 128B write lines). Verified R12.
__global__ void k_prep(const float* __restrict__ x, bf16_t* __restrict__ xb,
                       const float* __restrict__ Wq, const float* __restrict__ Wk,
                       const float* __restrict__ Wv, const float* __restrict__ Wo,
                       bf16_t* __restrict__ WqkvT, bf16_t* __restrict__ WoT) {
  const int z = blockIdx.z;
  if (z < 4) {
    __shared__ float t[64][65];
    const float* W = z == 0 ? Wq : z == 1 ? Wk : z == 2 ? Wv : Wo;
    bf16_t* Wt = z < 3 ? WqkvT + (size_t)z * D_MODEL * D_MODEL : WoT;
    int k0 = blockIdx.x * 64, n0 = blockIdx.y * 64;
    int tx = threadIdx.x, ty = threadIdx.y;
#pragma unroll
    for (int e = 0; e < 16; ++e) {
      int r = ty + (e >> 1) * 8;
      int c = tx + (e & 1) * 32;
      t[r][c] = W[(size_t)(k0 + r) * D_MODEL + n0 + c];
    }
    __syncthreads();
#pragma unroll
    for (int e = 0; e < 8; ++e) {
      int rr = ty + e * 8;
      int cc = tx * 2;
      bf16x2 ov;
      ov[0] = (bf16_t)t[cc][rr];
      ov[1] = (bf16_t)t[cc + 1][rr];
      *(bf16x2*)(Wt + (size_t)(n0 + rr) * D_MODEL + k0 + cc) = ov;
    }
  } else {
    const int n4 = TOK * D_MODEL / 4;
    const int tid = threadIdx.y * 32 + threadIdx.x;
    int i = (blockIdx.y * 32 + blockIdx.x) * 256 + tid;
    const int stride = 32 * 32 * 256;
    for (; i < n4; i += stride) {
      float4 v = ((const float4*)x)[i];
      bf16x4 o;
      o[0] = (bf16_t)v.x; o[1] = (bf16_t)v.y; o[2] = (bf16_t)v.z; o[3] = (bf16_t)v.w;
      ((bf16x4*)xb)[i] = o;
    }
  }
}

// ---------------- 256x256 8-wave GEMM, 2-phase K-step (R6/R9-proven: 201us) ----------
// The ~46% MfmaUtil / 201us attractor survived EIGHT structural interventions:
// 5 schedules (R1-R5), L2 blocking (R6, FETCH 320->148MB, time flat), occupancy
// (R3/R7), and B-direct-from-L2 (R10: conflicts -33% but MfmaUtil 26%, +124us).
// This is the verified floor for this tile geometry. DO NOT restructure.
// launch_bounds stays (512,2): (512,4) caps VGPR at 128 -> acc spills (R3).
// MODE 0 writes Q pre-scaled by C = log2(e)/sqrt(128) (softmax scale folded).
template <int MODE>
__global__ __launch_bounds__(512, 2) void k_gemm256(const bf16_t* __restrict__ A,
                                                    const bf16_t* __restrict__ Bt,
                                                    const float* __restrict__ b0p,
                                                    const float* __restrict__ b1p,
                                                    const float* __restrict__ b2p,
                                                    void* __restrict__ o0,
                                                    void* __restrict__ o1,
                                                    void* __restrict__ o2) {
  constexpr int K = D_MODEL;
  constexpr int NTOT = (MODE == 0) ? 3 * D_MODEL : D_MODEL;
  constexpr int NT = K / 64; // 32 K-tiles
  constexpr int NBM = TOK / 256; // 32
  __shared__ __attribute__((aligned(16))) bf16_t sh[2][2][2][8192];

  const int bid = blockIdx.x;
  const int cpx = gridDim.x >> 3;
  const int swz = (bid & 7) * cpx + (bid >> 3);
  const int grp = swz / (NBM * 4);
  const int rem = swz % (NBM * 4);
  const int bm = rem >> 2;
  const int bn = grp * 4 + (rem & 3);

  const int tid = threadIdx.x;
  const int lane = tid & 63;
  const int w = tid >> 6;
  const int wm = w >> 2, wn = w & 3;
  const int lr = lane & 15, lg = lane >> 4;

  const bf16_t* Agl[2];
  const bf16_t* Bgl[2];
  int ldsg[2];
#pragma unroll
  for (int l = 0; l < 2; ++l) {
    int g = l * 512 + tid;
    int r = g >> 2, c = g & 3;
    int csw = c ^ ((r ^ (r >> 2)) & 3);
    Agl[l] = A + (size_t)(bm * 256 + r) * K + csw * 8;
    Bgl[l] = Bt + (size_t)(bn * 256 + r) * K + csw * 8;
    ldsg[l] = g * 8;
  }

  auto SA = [&](int buf, int t, int kh) {
    const int off = t * 64 + kh * 32;
#pragma unroll
    for (int l = 0; l < 2; ++l) gload_lds16(Agl[l] + off, &sh[buf][0][kh][ldsg[l]]);
  };
  auto SB = [&](int buf, int t, int kh) {
    const int off = t * 64 + kh * 32;
#pragma unroll
    for (int l = 0; l < 2; ++l) gload_lds16(Bgl[l] + off, &sh[buf][1][kh][ldsg[l]]);
  };

  int offA[8], offB[4];
  const int cx = lg ^ ((lr ^ (lr >> 2)) & 3);
#pragma unroll
  for (int i = 0; i < 8; ++i) offA[i] = (wm * 128 + i * 16 + lr) * 32 + cx * 8;
#pragma unroll
  for (int j = 0; j < 4; ++j) offB[j] = (wn * 64 + j * 16 + lr) * 32 + cx * 8;

  f32x4 acc[8][4] = {};
  bf16x8 af[8], bf_[4];

  SA(0, 0, 0); SB(0, 0, 0); SA(0, 0, 1); SB(0, 0, 1);

#define MFMA_ROW(i)                                  \
  acc[i][0] = MFMA16(af[i], bf_[0], acc[i][0]);      \
  acc[i][1] = MFMA16(af[i], bf_[1], acc[i][1]);      \
  acc[i][2] = MFMA16(af[i], bf_[2], acc[i][2]);      \
  acc[i][3] = MFMA16(af[i], bf_[3], acc[i][3]);

  for (int t = 0; t < NT; ++t) {
    const int cur = t & 1, nxt = cur ^ 1;
    const int t1 = (t + 1 < NT) ? t + 1 : NT - 1;
#pragma unroll
    for (int kh = 0; kh < 2; ++kh) {
      asm volatile("s_waitcnt vmcnt(4)" ::: "memory");
      __builtin_amdgcn_s_barrier();
#pragma unroll
      for (int j = 0; j < 4; ++j) bf_[j] = *(const bf16x8*)&sh[cur][1][kh][offB[j]];
#pragma unroll
      for (int i = 0; i < 8; ++i) af[i] = *(const bf16x8*)&sh[cur][0][kh][offA[i]];
      SA(nxt, t1, kh);
      SB(nxt, t1, kh);
      __builtin_amdgcn_s_setprio(1);
      asm volatile("s_waitcnt lgkmcnt(6)" ::: "memory");
      __builtin_amdgcn_sched_barrier(0);
      MFMA_ROW(0) MFMA_ROW(1)
      asm volatile("s_waitcnt lgkmcnt(4)" ::: "memory");
      __builtin_amdgcn_sched_barrier(0);
      MFMA_ROW(2) MFMA_ROW(3)
      asm volatile("s_waitcnt lgkmcnt(2)" ::: "memory");
      __builtin_amdgcn_sched_barrier(0);
      MFMA_ROW(4) MFMA_ROW(5)
      asm volatile("s_waitcnt lgkmcnt(0)" ::: "memory");
      __builtin_amdgcn_sched_barrier(0);
      MFMA_ROW(6) MFMA_ROW(7)
      __builtin_amdgcn_s_setprio(0);
    }
  }
#undef MFMA_ROW

  asm volatile("s_waitcnt vmcnt(0) lgkmcnt(0)" ::: "memory");

  // ---- epilogue ----
  const float CQ = 0.12751949848078418f; // (1/sqrt(128)) * log2(e), folded into Q
#pragma unroll
  for (int i = 0; i < 8; ++i) {
    const int row = bm * 256 + wm * 128 + i * 16 + lg * 4;
#pragma unroll
    for (int jn = 0; jn < 4; ++jn) {
      const int col = bn * 256 + wn * 64 + jn * 16 + lr;
      if (MODE == 1) {
        const float bv = b0p[col];
        float* Cf = (float*)o0;
#pragma unroll
        for (int j = 0; j < 4; ++j)
          Cf[(size_t)(row + j) * D_MODEL + col] = acc[i][jn][j] + bv;
      } else {
        const int sel = col >> 11, cl = col & 2047;
        const float bv = (sel == 0 ? b0p : sel == 1 ? b1p : b2p)[cl];
        if (sel < 2) {
          const float scl = (sel == 0) ? CQ : 1.0f;
          bf16_t* dst = (bf16_t*)(sel == 0 ? o0 : o1);
#pragma unroll
          for (int j = 0; j < 4; ++j)
            dst[(size_t)(row + j) * D_MODEL + cl] = (bf16_t)((acc[i][jn][j] + bv) * scl);
        } else {
          const int bb2 = row >> 11, s = row & 2047;
          bf16x4 ov;
#pragma unroll
          for (int j = 0; j < 4; ++j) ov[j] = (bf16_t)(acc[i][jn][j] + bv);
          bf16_t* Vt = (bf16_t*)o2;
          *(bf16x4*)(Vt + (((size_t)(bb2 * 16 + (cl >> 7))) * 128 + (cl & 127)) * 2048 + s) = ov;
        }
      }
    }
  }
}

// -------- causal flash attention: swapped 32x32, KVBLK=32, 3-slot ring (R15-champion) --------
// 1024 blocks: fid -> qb = 15 - fid/64 (heaviest first), bh = fid & 63.
// 4 waves x QBLK=32. 3-slot LDS ring (48 KiB, 3 blocks/CU), staging leads by 2
// tiles, counted vmcnt(4) + raw s_barrier. Q arrives pre-scaled by C.
// Per-lane lsum partial (epilogue shfl); defer threshold 12.5.
// Attn scaling is CLOSED both ways: 8-wave/QROWS=256 (R16) regressed +20us
// (latency/occupancy-bound, K/V L3-resident so traffic halving doesn't pay);
// 2-q-group register sharing failed verification twice (R8/R13).
__global__ __launch_bounds__(256, 3) void k_attn(const bf16_t* __restrict__ Q,
                                                 const bf16_t* __restrict__ K,
                                                 const bf16_t* __restrict__ Vt,
                                                 bf16_t* __restrict__ AO) {
  const int fid = blockIdx.x;
  const int qb = 15 - (fid >> 6);
  const int bh = fid & 63;
  const int b = bh >> 4, h = bh & 15;
  const int w = threadIdx.x >> 6, lane = threadIdx.x & 63;
  const int l31 = lane & 31, hl = lane >> 5;
  const int nt = 4 * qb + 4; // >= 4 always

  __shared__ __attribute__((aligned(16))) bf16_t Ks[3][32 * 128];
  __shared__ __attribute__((aligned(16))) bf16_t Vs[3][128 * 32];

  const bf16_t* kbase = K + (size_t)(b * SEQ) * D_MODEL + h * HEAD_DIM;
  const bf16_t* vtbase = Vt + (size_t)bh * HEAD_DIM * SEQ;

  auto STAGE = [&](int buf, int kt) {
    const int tt = threadIdx.x;
#pragma unroll
    for (int p = 0; p < 2; ++p) {
      int g = p * 256 + tt;
      int r = g >> 4, c = g & 15;
      gload_lds16(kbase + (size_t)(kt * 32 + r) * D_MODEL + ((c ^ (r & 7)) * 8),
                  &Ks[buf][(size_t)(g & ~63) * 8]);
    }
#pragma unroll
    for (int p = 0; p < 2; ++p) {
      int g = p * 256 + tt;
      int r = g >> 2, c = g & 3;
      gload_lds16(vtbase + (size_t)r * SEQ + kt * 32 + ((c ^ ((r ^ (r >> 2)) & 3)) * 8),
                  &Vs[buf][(size_t)(g & ~63) * 8]);
    }
  };

  const int qw0 = qb * 128 + w * 32;
  const int qa = qw0 + l31;

  const bf16_t* qp = Q + (size_t)(b * SEQ + qa) * D_MODEL + h * HEAD_DIM + hl * 8;
  bf16x8 qf[8];
#pragma unroll
  for (int step = 0; step < 8; ++step) qf[step] = *(const bf16x8*)(qp + step * 16);

  f32x16 oacc[4];
#pragma unroll
  for (int db = 0; db < 4; ++db)
#pragma unroll
    for (int r = 0; r < 16; ++r) oacc[db][r] = 0.f;
  float m = -1e30f, lsum = 0.f; // lsum: LANE-LOCAL partial (combined in epilogue)

  STAGE(0, 0);
  STAGE(1, 1); // nt >= 4, always valid

  int cur = 0, stg = 2; // stage slot = (kt+2) % 3
  for (int kt = 0; kt < nt; ++kt) {
    if (kt < nt - 1) {
      asm volatile("s_waitcnt vmcnt(4)" ::: "memory"); // stage(kt) landed
    } else {
      asm volatile("s_waitcnt vmcnt(0)" ::: "memory"); // final tile
    }
    __builtin_amdgcn_s_barrier();
    asm volatile("" ::: "memory");
    if (kt + 2 < nt) STAGE(stg, kt + 2);

    if (kt * 32 < qw0 + 32) {
      // ---- swapped QK^T (Q pre-scaled by C in GEMM epilogue) ----
      f32x16 sacc;
#pragma unroll
      for (int r = 0; r < 16; ++r) sacc[r] = 0.f;
      const bf16_t* kr = &Ks[cur][l31 * 128];
      const int rx = l31 & 7;
      __builtin_amdgcn_s_setprio(1);
#pragma unroll
      for (int step = 0; step < 8; ++step) {
        bf16x8 kf = *(const bf16x8*)(kr + (((step * 2 + hl) ^ rx) * 8));
        sacc = MFMA32(kf, qf[step], sacc);
      }
      __builtin_amdgcn_s_setprio(0);

      // ---- mask + tile max (max3-fused tree) ----
      const bool domask = (kt * 32 + 31 > qw0);
      if (domask) {
#pragma unroll
        for (int r = 0; r < 16; ++r) {
          int kv = kt * 32 + 4 * hl + (r & 3) + 8 * (r >> 2);
          if (kv > qa) sacc[r] = -1e30f;
        }
      }
      float mx8[8];
#pragma unroll
      for (int r = 0; r < 8; ++r) mx8[r] = fmaxf(sacc[r], sacc[r + 8]);
      float t0 = fmaxf(fmaxf(mx8[0], mx8[1]), mx8[2]);
      float t1 = fmaxf(fmaxf(mx8[3], mx8[4]), mx8[5]);
      float t2 = fmaxf(fmaxf(mx8[6], mx8[7]), t0);
      float tm = fmaxf(t1, t2);
      tm = fmaxf(tm, __shfl_xor(tm, 32));

      // ---- defer-max rescale (threshold 12.5: P <= 2^12.5, f32/bf16-safe) ----
      if (!__all(tm <= m + 12.5f)) {
        const float mn = fmaxf(m, tm);
        const float al = fast_exp2(m - mn);
        lsum *= al;
#pragma unroll
        for (int db = 0; db < 4; ++db)
#pragma unroll
          for (int r = 0; r < 16; ++r) oacc[db][r] *= al;
        m = mn;
      }

      // ---- P = exp2(S - m), lane-local sum (tree) ----
#pragma unroll
      for (int r = 0; r < 16; ++r) sacc[r] = fast_exp2(sacc[r] - m);
      float sm8[8];
#pragma unroll
      for (int r = 0; r < 8; ++r) sm8[r] = sacc[r] + sacc[r + 8];
#pragma unroll
      for (int r = 0; r < 4; ++r) sm8[r] = sm8[r] + sm8[r + 4];
      lsum += (sm8[0] + sm8[1]) + (sm8[2] + sm8[3]);

      // ---- P^T -> bf16 B-operand (shfl_xor exchange) ----
      bf16x8 pb[2];
#pragma unroll
      for (int ck = 0; ck < 2; ++ck) {
        u32 a0 = pack2(sacc[8 * ck + 0], sacc[8 * ck + 1]);
        u32 a1 = pack2(sacc[8 * ck + 2], sacc[8 * ck + 3]);
        u32 b0 = pack2(sacc[8 * ck + 4], sacc[8 * ck + 5]);
        u32 b1 = pack2(sacc[8 * ck + 6], sacc[8 * ck + 7]);
        u32 send0 = hl ? a0 : b0, send1 = hl ? a1 : b1;
        u32 keep0 = hl ? b0 : a0, keep1 = hl ? b1 : a1;
        u32 r0 = __shfl_xor(send0, 32), r1 = __shfl_xor(send1, 32);
        u32x4 fv;
        fv[0] = hl ? r0 : keep0;
        fv[1] = hl ? r1 : keep1;
        fv[2] = hl ? keep0 : r0;
        fv[3] = hl ? keep1 : r1;
        pb[ck] = __builtin_bit_cast(bf16x8, fv);
      }

      // ---- PV ----
      __builtin_amdgcn_s_setprio(1);
#pragma unroll
      for (int db = 0; db < 4; ++db) {
        const int vrow = db * 32 + l31;
        const bf16_t* vr = &Vs[cur][vrow * 32];
        const int vx = (vrow ^ (vrow >> 2)) & 3;
#pragma unroll
        for (int ck = 0; ck < 2; ++ck) {
          bf16x8 vf = *(const bf16x8*)(vr + (((ck * 2 + hl) ^ vx) * 8));
          oacc[db] = MFMA32(vf, pb[ck], oacc[db]);
        }
      }
      __builtin_amdgcn_s_setprio(0);
    }

    cur = (cur == 2) ? 0 : cur + 1;
    stg = (stg == 2) ? 0 : stg + 1;
  }

  // ---- epilogue (combine lane-pair lsum partials once) ----
  const float inv = 1.f / (lsum + __shfl_xor(lsum, 32));
  bf16_t* ao = AO + (size_t)(b * SEQ + qa) * D_MODEL + h * HEAD_DIM;
#pragma unroll
  for (int db = 0; db < 4; ++db)
#pragma unroll
    for (int g = 0; g < 4; ++g) {
      bf16x4 ov;
#pragma unroll
      for (int j = 0; j < 4; ++j) ov[j] = (bf16_t)(oacc[db][4 * g + j] * inv);
      *(bf16x4*)(ao + db * 32 + 8 * g + 4 * hl) = ov;
    }
}

// ---------------- launch ----------------
extern "C" void kernel_launch(void* const* d_in, const int* in_sizes, int n_in,
                              void* d_out, int out_size, void* d_ws, size_t ws_size,
                              hipStream_t stream) {
  const float* x  = (const float*)d_in[0];
  const float* Wq = (const float*)d_in[1];
  const float* bq = (const float*)d_in[2];
  const float* Wk = (const float*)d_in[3];
  const float* bk = (const float*)d_in[4];
  const float* Wv = (const float*)d_in[5];
  const float* bv = (const float*)d_in[6];
  const float* Wo = (const float*)d_in[7];
  const float* bo = (const float*)d_in[8];

  const size_t SZ_X = (size_t)TOK * D_MODEL * sizeof(bf16_t);       // 32 MB
  const size_t SZ_W = (size_t)D_MODEL * D_MODEL * sizeof(bf16_t);   // 8 MB

  char* p = (char*)d_ws;
  bf16_t* xb    = (bf16_t*)p;                     p += SZ_X;
  bf16_t* WqkvT = (bf16_t*)p;                     p += 3 * SZ_W;
  bf16_t* WoT   = (bf16_t*)p;                     p += SZ_W;
  bf16_t* Qm    = (bf16_t*)p;                     p += SZ_X;
  bf16_t* Km    = (bf16_t*)p;                     p += SZ_X;
  bf16_t* Vt    = (bf16_t*)p;                     p += SZ_X;
  bf16_t* AO    = xb;  // xb dead after QKV GEMM

  // merged cvt + weight transpose (z=0..3 transpose 64x64, z=4 cvt)
  k_prep<<<dim3(32, 32, 5), dim3(32, 8), 0, stream>>>(x, xb, Wq, Wk, Wv, Wo, WqkvT, WoT);

  const int gqkv = (TOK / 256) * (3 * D_MODEL / 256); // 32*24 = 768
  k_gemm256<0><<<gqkv, 512, 0, stream>>>(xb, WqkvT, bq, bk, bv, Qm, Km, Vt);

  k_attn<<<1024, 256, 0, stream>>>(Qm, Km, Vt, AO);

  const int go = (TOK / 256) * (D_MODEL / 256); // 256
  k_gemm256<1><<<go, 512, 0, stream>>>(AO, WoT, bo, nullptr, nullptr, d_out, nullptr, nullptr);
}